// Round 12
// baseline (6040.010 us; speedup 1.0000x reference)
//
#include <hip/hip_runtime.h>
#include <cmath>

typedef _Float16 f16;
typedef _Float16 f16x8 __attribute__((ext_vector_type(8)));
typedef _Float16 f16x4 __attribute__((ext_vector_type(4)));
typedef float f32x4 __attribute__((ext_vector_type(4)));
typedef unsigned long long u64;

#define H_DIM 1024
#define I_DIMM 256
#define B_DIM 64
#define T_DIM 256
#define K_DIM 1280
#define NBLK 128   // blocks; each owns 8 h-cols
#define SLABSZ (B_DIM * H_DIM)   // one h slab, f16 elements (128 KB)

// Build W16[4096][1280] = fp16([Whh | Wih]) row-major. grid = 4096 blocks.
__global__ __launch_bounds__(256) void conv_w_kernel(const float* __restrict__ Whh,
                                                     const float* __restrict__ Wih,
                                                     f16* __restrict__ W16) {
    const int r = blockIdx.x;
    const int tid = threadIdx.x;
    const float* hh = Whh + (size_t)r * H_DIM;
    const float* ih = Wih + (size_t)r * I_DIMM;
    f16* dst = W16 + (size_t)r * K_DIM;
    for (int k = tid; k < K_DIM; k += 256)
        dst[k] = (f16)(k < H_DIM ? hh[k] : ih[k - H_DIM]);
}

// x fp32 -> fp16, vectorized 4-wide. n4 = total/4.
__global__ __launch_bounds__(256) void conv_x_kernel(const float* __restrict__ x,
                                                     f16* __restrict__ x16, int n4) {
    const int i = blockIdx.x * 256 + threadIdx.x;
    if (i < n4) {
        float4 v = ((const float4*)x)[i];
        f16x4 o;
        o[0] = (f16)v.x; o[1] = (f16)v.y; o[2] = (f16)v.z; o[3] = (f16)v.w;
        ((f16x4*)x16)[i] = o;
    }
}

// sigmoid / tanh via v_exp_f32 + v_rcp_f32 (exact identities)
__device__ __forceinline__ float fsig(float x) {
    return __builtin_amdgcn_rcpf(1.f + __builtin_amdgcn_exp2f(-1.442695041f * x));
}
__device__ __forceinline__ float ftanh(float x) {
    return 1.f - 2.f * __builtin_amdgcn_rcpf(1.f + __builtin_amdgcn_exp2f(2.885390082f * x));
}

__device__ __forceinline__ bool is_sent(u64 v) {
    return ((unsigned)v == 0xFFFFFFFFu) || ((unsigned)(v >> 32) == 0xFFFFFFFFu);
}

// Persistent LSTM, both phases, 512 steps, one cooperative launch.
// ROUND-12 CHANGE (single axis vs round-11 verified kernel): the flag-array
// grid barrier is replaced by SENTINEL-POLL dataflow sync.
//   - h lives in a ring of 4 step-indexed slabs hR[su&3][64][1024].
//   - unwritten slab bytes = 0xFF (f16 NaN, unproducible by o*tanh(c));
//     consumer's h-burst re-loads any u64 whose u32 half == 0xFFFFFFFF
//     (per-u32 check defeats dword tearing). The load IS the barrier.
//   - producer publishes (sc1 write-through) and moves on: no flag store,
//     no post-publish drain.
//   - ring reuse: during step su (after the gpart __syncthreads proves the
//     whole block's poll of slab su finished => all blocks consumed slab
//     su-1), tid<128 re-sentinel the block's own slice of slab (su-1)&3.
//     The pre-publish vmcnt(0) drains sentinels before the publish is
//     observable -> sentinel precedes any data-rewrite at reuse (su+3).
//     Max inter-block skew is 1 step, so ring-4 is ample.
// Everything else (512 threads = 8 waves (bh,kq), W staging, MFMA, gpart
// stride 34, fsig/ftanh activations, publish addressing) is byte-identical
// to round 11.
__global__ __launch_bounds__(512, 1) void lstm_persistent(
    f16* __restrict__ hR,            // [4][64][1024] ring
    const f16* __restrict__ x16,     // [64][256][256]
    const f16* __restrict__ W16e,    // [4096][1280]
    const f16* __restrict__ W16d,    // [4096][1280]
    const float* __restrict__ enc_bih, const float* __restrict__ enc_bhh,
    const float* __restrict__ dec_bih, const float* __restrict__ dec_bhh)
{
    __shared__ __align__(16) f16 lds_w[2][40][64][8];   // 80 KB  [ct][chunk][lane][8]
    __shared__ float gpart[4][64][34];                  // 34.8 KB [kq][batch][gatecol]
    __shared__ __align__(16) f16 h_lds[64][8];          // 1 KB

    const int tid  = threadIdx.x;
    const int blk  = blockIdx.x;
    const int w    = tid >> 6;
    const int bh   = w >> 2;              // batch half (0: rows 0-31, 1: 32-63)
    const int kq   = w & 3;               // K quarter
    const int lane = tid & 63;
    const int n    = lane & 15;
    const int kg   = lane >> 4;
    const int kg8  = kg * 8;
    const int kq32 = kq * 32;

    // W rows for this lane's two column-tiles (gate-col = ct*16 + n)
    int rW[2];
    #pragma unroll
    for (int ct = 0; ct < 2; ++ct) {
        const int gc = ct * 16 + n;
        rW[ct] = (gc >> 3) * H_DIM + blk * 8 + (gc & 7);
    }

    // activation-thread mapping: one (batch, col) per thread
    const int ab   = tid >> 3;
    const int aj   = tid & 7;
    const int acol = blk * 8 + aj;

    float c_reg = 0.f;                    // cell state, carries enc -> dec

    #pragma unroll 1
    for (int phase = 0; phase < 2; ++phase) {
        const f16* W  = phase ? W16d : W16e;
        const float* bi = phase ? dec_bih : enc_bih;
        const float* bhp = phase ? dec_bhh : enc_bhh;

        float bsum[4];
        #pragma unroll
        for (int g = 0; g < 4; ++g)
            bsum[g] = bi[g * H_DIM + acol] + bhp[g * H_DIM + acol];

        // Stage W chunks: bh=0 waves stage iters 0..4, bh=1 waves iters 5..9.
        {
            const int it0 = bh * 5;
            #pragma unroll 1
            for (int i = 0; i < 5; ++i) {
                const int c = (it0 + i) * 4 + kq;
                #pragma unroll
                for (int ct = 0; ct < 2; ++ct)
                    *(f16x8*)&lds_w[ct][c][lane][0] =
                        *(const f16x8*)(W + (size_t)rW[ct] * K_DIM + c * 32 + kg8);
            }
        }
        __syncthreads();

        #pragma unroll 1
        for (int t = 0; t < T_DIM; ++t) {
            const int su = phase * 256 + t;                 // global step
            const f16* slab_in  = hR + (size_t)(su & 3) * SLABSZ;
            f16*       slab_out = hR + (size_t)((su + 1) & 3) * SLABSZ;
            const f16* xt = x16 + (size_t)t * I_DIMM;

            f32x4 acc[2][2];   // [ct][btl]
            #pragma unroll
            for (int ct = 0; ct < 2; ++ct)
                #pragma unroll
                for (int btl = 0; btl < 2; ++btl)
                    acc[ct][btl] = (f32x4){0.f, 0.f, 0.f, 0.f};

            // ---- x-part (h-independent): front-runs the h arrival ----
            #pragma unroll
            for (int it = 8; it < 10; ++it) {
                const int c  = it * 4 + kq;
                const int xo = c * 32 - 1024 + kg8;
                f16x8 wf0 = *(const f16x8*)&lds_w[0][c][lane][0];
                f16x8 wf1 = *(const f16x8*)&lds_w[1][c][lane][0];
                #pragma unroll
                for (int btl = 0; btl < 2; ++btl) {
                    const int btg = bh * 2 + btl;
                    f16x8 a = *(const f16x8*)(xt + (size_t)(n + 16 * btg) * (T_DIM * I_DIMM) + xo);
                    acc[0][btl] = __builtin_amdgcn_mfma_f32_16x16x32_f16(a, wf0, acc[0][btl], 0, 0, 0);
                    acc[1][btl] = __builtin_amdgcn_mfma_f32_16x16x32_f16(a, wf1, acc[1][btl], 0, 0, 0);
                }
            }

            // ---- sentinel-poll h burst: the data IS the barrier ----
            u64 hb[32];
            #pragma unroll
            for (int i = 0; i < 32; ++i) hb[i] = ~0ull;
            {
                bool pending = true;
                while (pending) {
                    bool any = false;
                    #pragma unroll
                    for (int it = 0; it < 8; ++it) {
                        #pragma unroll
                        for (int btl = 0; btl < 2; ++btl) {
                            const int btg = bh * 2 + btl;
                            const u64* p = (const u64*)(slab_in + it * 128 + kq32 + kg8
                                                        + (size_t)(n + 16 * btg) * H_DIM);
                            const int ix = (it * 2 + btl) * 2;
                            #pragma unroll
                            for (int q = 0; q < 2; ++q) {
                                if (is_sent(hb[ix + q])) {
                                    u64 v = __hip_atomic_load(p + q, __ATOMIC_RELAXED,
                                                              __HIP_MEMORY_SCOPE_AGENT);
                                    hb[ix + q] = v;
                                    if (is_sent(v)) any = true;
                                }
                            }
                        }
                    }
                    pending = any;
                    if (any) __builtin_amdgcn_s_sleep(1);
                }
            }

            // ---- h-part MFMAs ----
            #pragma unroll
            for (int it = 0; it < 8; ++it) {
                const int c = it * 4 + kq;
                f16x8 wf0 = *(const f16x8*)&lds_w[0][c][lane][0];
                f16x8 wf1 = *(const f16x8*)&lds_w[1][c][lane][0];
                #pragma unroll
                for (int btl = 0; btl < 2; ++btl) {
                    union { u64 u[2]; f16x8 v; } U;
                    U.u[0] = hb[(it * 2 + btl) * 2 + 0];
                    U.u[1] = hb[(it * 2 + btl) * 2 + 1];
                    acc[0][btl] = __builtin_amdgcn_mfma_f32_16x16x32_f16(U.v, wf0, acc[0][btl], 0, 0, 0);
                    acc[1][btl] = __builtin_amdgcn_mfma_f32_16x16x32_f16(U.v, wf1, acc[1][btl], 0, 0, 0);
                }
            }

            // partials: D row = (bh*2+btl)*16 + kg*4 + r, col = ct*16 + n
            #pragma unroll
            for (int ct = 0; ct < 2; ++ct)
                #pragma unroll
                for (int btl = 0; btl < 2; ++btl)
                    #pragma unroll
                    for (int r = 0; r < 4; ++r)
                        gpart[kq][(bh * 2 + btl) * 16 + kg * 4 + r][ct * 16 + n] = acc[ct][btl][r];
            __syncthreads();
            // ^ this barrier also proves: every thread's poll of slab su done
            //   => all blocks published slab su => all consumed slab su-1.

            // ---- re-sentinel slab su-1 (ring reuse), own 8-col slice ----
            if (su > 0 && tid < 128) {
                const int b = tid >> 1, half = tid & 1;
                u64* dst = (u64*)(hR + (size_t)((su - 1) & 3) * SLABSZ
                                  + (size_t)b * H_DIM + blk * 8 + half * 4);
                __hip_atomic_store(dst, ~0ull, __ATOMIC_RELAXED, __HIP_MEMORY_SCOPE_AGENT);
            }

            // ---- activations + state update: one (batch, col) per thread ----
            {
                float pre[4];
                #pragma unroll
                for (int g = 0; g < 4; ++g)
                    pre[g] = gpart[0][ab][g * 8 + aj] + gpart[1][ab][g * 8 + aj]
                           + gpart[2][ab][g * 8 + aj] + gpart[3][ab][g * 8 + aj] + bsum[g];
                const float i_ = fsig(pre[0]);
                const float f_ = fsig(pre[1]);
                const float g_ = ftanh(pre[2]);
                const float o_ = fsig(pre[3]);
                c_reg = f_ * c_reg + i_ * g_;
                h_lds[ab][aj] = (f16)(o_ * ftanh(c_reg));
            }
            __syncthreads();

            // sentinels (and consumed poll loads) must be at LLC before the
            // publish below is observable -> per-wave drain, then publish.
            asm volatile("s_waitcnt vmcnt(0)" ::: "memory");

            // ---- publish this block's 8 h-cols; NO drain, NO flag ----
            if (tid < 128) {
                const int b = tid >> 1, half = tid & 1;
                u64 v = *(const u64*)&h_lds[b][half * 4];
                __hip_atomic_store((u64*)(slab_out + (size_t)b * H_DIM + blk * 8 + half * 4), v,
                                   __ATOMIC_RELAXED, __HIP_MEMORY_SCOPE_AGENT);
            }
            __syncthreads();   // protect h_lds rewrite next iteration
        }
    }
}

// Tail MLP: a = PReLU(additional @ fcc_W^T + fcc_b); out[b] = [dh, a] @ fc_W^T + fc_b
// Final dec h = slab (512)&3 = 0, i.e. hR base, layout [64][1024].
__global__ __launch_bounds__(256) void tail_kernel(
    const f16* __restrict__ dh,        // [64][1024] fp16
    const float* __restrict__ addl,    // [64][128]
    const float* __restrict__ fccW,    // [256][128]
    const float* __restrict__ fccb,    // [256]
    const float* __restrict__ fcW,     // [1][1280]
    const float* __restrict__ fcb,     // [1]
    const float* __restrict__ prelu_a, // [1]
    float* __restrict__ out)           // [64]
{
    __shared__ float a_lds[256];
    __shared__ float red[256];
    const int b = blockIdx.x;
    const int t = threadIdx.x;

    float s = fccb[t];
    const float* wr = fccW + t * 128;
    const float* ar = addl + b * 128;
    #pragma unroll 4
    for (int k = 0; k < 128; ++k) s += ar[k] * wr[k];
    const float pa = *prelu_a;
    a_lds[t] = (s >= 0.f) ? s : pa * s;
    __syncthreads();

    float acc = 0.f;
    for (int k = t; k < 1024; k += 256) acc += (float)dh[b * H_DIM + k] * fcW[k];
    acc += a_lds[t] * fcW[1024 + t];
    red[t] = acc;
    __syncthreads();
    for (int sft = 128; sft > 0; sft >>= 1) {
        if (t < sft) red[t] += red[t + sft];
        __syncthreads();
    }
    if (t == 0) out[b] = red[0] + fcb[0];
}

extern "C" void kernel_launch(void* const* d_in, const int* in_sizes, int n_in,
                              void* d_out, int out_size, void* d_ws, size_t ws_size,
                              hipStream_t stream)
{
    const float* x       = (const float*)d_in[0];
    const float* addl    = (const float*)d_in[1];
    const float* enc_Wih = (const float*)d_in[2];
    const float* enc_Whh = (const float*)d_in[3];
    const float* enc_bih = (const float*)d_in[4];
    const float* enc_bhh = (const float*)d_in[5];
    const float* dec_Wih = (const float*)d_in[6];
    const float* dec_Whh = (const float*)d_in[7];
    const float* dec_bih = (const float*)d_in[8];
    const float* dec_bhh = (const float*)d_in[9];
    const float* fcc_W   = (const float*)d_in[10];
    const float* fcc_b   = (const float*)d_in[11];
    const float* fc_W    = (const float*)d_in[12];
    const float* fc_b    = (const float*)d_in[13];
    const float* prelu_a = (const float*)d_in[14];

    char* wsb = (char*)d_ws;
    const size_t W16_BYTES = (size_t)4 * H_DIM * K_DIM * sizeof(f16);   // 10.5 MB
    const size_t X16_BYTES = (size_t)B_DIM * T_DIM * I_DIMM * sizeof(f16);
    const size_t SLAB_BYTES = (size_t)SLABSZ * sizeof(f16);             // 128 KB

    f16* W16e = (f16*)wsb;                      wsb += W16_BYTES;
    f16* W16d = (f16*)wsb;                      wsb += W16_BYTES;
    f16* x16  = (f16*)wsb;                      wsb += X16_BYTES;
    f16* hR   = (f16*)wsb;                      wsb += 4 * SLAB_BYTES;

    // One-time (per call) conversions + ring init.
    conv_w_kernel<<<4 * H_DIM, 256, 0, stream>>>(enc_Whh, enc_Wih, W16e);
    conv_w_kernel<<<4 * H_DIM, 256, 0, stream>>>(dec_Whh, dec_Wih, W16d);
    conv_x_kernel<<<(B_DIM * T_DIM * I_DIMM / 4 + 255) / 256, 256, 0, stream>>>(
        x, x16, B_DIM * T_DIM * I_DIMM / 4);
    hipMemsetAsync(hR, 0x00, SLAB_BYTES, stream);               // slab 0 = h_init = 0
    hipMemsetAsync(hR + SLABSZ, 0xFF, 3 * SLAB_BYTES, stream);  // slabs 1..3 = sentinel

    // Persistent cooperative kernel: both LSTMs, 512 steps, one launch.
    {
        void* args[] = { &hR, &x16, &W16e, &W16d,
                         &enc_bih, &enc_bhh, &dec_bih, &dec_bhh };
        hipLaunchCooperativeKernel((void*)lstm_persistent, dim3(NBLK), dim3(512),
                                   args, 0, stream);
    }

    // Final dec h is slab 0 (512 steps, 512 & 3 == 0).
    tail_kernel<<<64, 256, 0, stream>>>(hR, addl, fcc_W, fcc_b, fc_W, fc_b,
                                        prelu_a, (float*)d_out);
}

// Round 13
// 2555.563 us; speedup vs baseline: 2.3635x; 2.3635x over previous
//
#include <hip/hip_runtime.h>
#include <cmath>

typedef _Float16 f16;
typedef _Float16 f16x8 __attribute__((ext_vector_type(8)));
typedef _Float16 f16x4 __attribute__((ext_vector_type(4)));
typedef float f32x4 __attribute__((ext_vector_type(4)));
typedef unsigned long long u64;

#define H_DIM 1024
#define I_DIMM 256
#define B_DIM 64
#define T_DIM 256
#define K_DIM 1280
#define NBLK 128                  // blocks; each owns 8 h-cols
#define SLABSZ (NBLK * 64 * 8)    // one h slab, f16 elements (128 KB)
#define FSTRIDE 64                // flag padding: 64 u32 = 256 B per block

// Build W16[4096][1280] = fp16([Whh | Wih]) row-major. grid = 4096 blocks.
__global__ __launch_bounds__(256) void conv_w_kernel(const float* __restrict__ Whh,
                                                     const float* __restrict__ Wih,
                                                     f16* __restrict__ W16) {
    const int r = blockIdx.x;
    const int tid = threadIdx.x;
    const float* hh = Whh + (size_t)r * H_DIM;
    const float* ih = Wih + (size_t)r * I_DIMM;
    f16* dst = W16 + (size_t)r * K_DIM;
    for (int k = tid; k < K_DIM; k += 256)
        dst[k] = (f16)(k < H_DIM ? hh[k] : ih[k - H_DIM]);
}

// x fp32 -> fp16, vectorized 4-wide. n4 = total/4.
__global__ __launch_bounds__(256) void conv_x_kernel(const float* __restrict__ x,
                                                     f16* __restrict__ x16, int n4) {
    const int i = blockIdx.x * 256 + threadIdx.x;
    if (i < n4) {
        float4 v = ((const float4*)x)[i];
        f16x4 o;
        o[0] = (f16)v.x; o[1] = (f16)v.y; o[2] = (f16)v.z; o[3] = (f16)v.w;
        ((f16x4*)x16)[i] = o;
    }
}

// sigmoid / tanh via v_exp_f32 + v_rcp_f32 (exact identities)
__device__ __forceinline__ float fsig(float x) {
    return __builtin_amdgcn_rcpf(1.f + __builtin_amdgcn_exp2f(-1.442695041f * x));
}
__device__ __forceinline__ float ftanh(float x) {
    return 1.f - 2.f * __builtin_amdgcn_rcpf(1.f + __builtin_amdgcn_exp2f(2.885390082f * x));
}

// Persistent LSTM, both phases, 512 steps, one cooperative launch.
// SYNC LOGIC IS BIT-IDENTICAL to the round-11 verified kernel (4.98 ms):
// x-part first (overlaps barrier wait) -> flag poll -> h burst -> h MFMAs ->
// gpart reduce -> activations -> publish -> vmcnt(0) -> flag store.
// ROUND-13 CHANGES (addressing only, anti line-contention):
//   (1) flags padded to 256 B per block (flags[blk*64]) -> 128 distinct LLC
//       lines for arrivals and 1:1 polls (was 4 shared lines).
//   (2) h exchange in BLOCK-MAJOR slabs hX[parity][pb][64][8]: producer owns
//       8 exclusive lines (contiguous 1 KB); was [64][1024] where every
//       128B line took interleaved 8B stores from 8 different CUs.
__global__ __launch_bounds__(512, 1) void lstm_persistent(
    f16* __restrict__ hX,            // [2][NBLK][64][8] ping-pong slabs
    const f16* __restrict__ x16,     // [64][256][256]
    const f16* __restrict__ W16e,    // [4096][1280]
    const f16* __restrict__ W16d,    // [4096][1280]
    const float* __restrict__ enc_bih, const float* __restrict__ enc_bhh,
    const float* __restrict__ dec_bih, const float* __restrict__ dec_bhh,
    unsigned* __restrict__ flags)    // [NBLK*FSTRIDE], zeroed each call
{
    __shared__ __align__(16) f16 lds_w[2][40][64][8];   // 80 KB  [ct][chunk][lane][8]
    __shared__ float gpart[4][64][34];                  // 34.8 KB [kq][batch][gatecol]
    __shared__ __align__(16) f16 h_lds[64][8];          // 1 KB

    const int tid  = threadIdx.x;
    const int blk  = blockIdx.x;
    const int w    = tid >> 6;
    const int bh   = w >> 2;              // batch half (0: rows 0-31, 1: 32-63)
    const int kq   = w & 3;               // K quarter
    const int lane = tid & 63;
    const int n    = lane & 15;
    const int kg   = lane >> 4;
    const int kg8  = kg * 8;

    // W rows for this lane's two column-tiles (gate-col = ct*16 + n)
    int rW[2];
    #pragma unroll
    for (int ct = 0; ct < 2; ++ct) {
        const int gc = ct * 16 + n;
        rW[ct] = (gc >> 3) * H_DIM + blk * 8 + (gc & 7);
    }

    // activation-thread mapping: one (batch, col) per thread
    const int ab   = tid >> 3;
    const int aj   = tid & 7;
    const int acol = blk * 8 + aj;

    float c_reg = 0.f;                    // cell state, carries enc -> dec
    unsigned stepv = 0;                   // monotone barrier epoch

    #pragma unroll 1
    for (int phase = 0; phase < 2; ++phase) {
        const f16* W  = phase ? W16d : W16e;
        const float* bi = phase ? dec_bih : enc_bih;
        const float* bhp = phase ? dec_bhh : enc_bhh;

        float bsum[4];
        #pragma unroll
        for (int g = 0; g < 4; ++g)
            bsum[g] = bi[g * H_DIM + acol] + bhp[g * H_DIM + acol];

        // Stage W chunks: bh=0 waves stage iters 0..4, bh=1 waves iters 5..9.
        {
            const int it0 = bh * 5;
            #pragma unroll 1
            for (int i = 0; i < 5; ++i) {
                const int c = (it0 + i) * 4 + kq;
                #pragma unroll
                for (int ct = 0; ct < 2; ++ct)
                    *(f16x8*)&lds_w[ct][c][lane][0] =
                        *(const f16x8*)(W + (size_t)rW[ct] * K_DIM + c * 32 + kg8);
            }
        }
        __syncthreads();

        #pragma unroll 1
        for (int t = 0; t < T_DIM; ++t) {
            // slab parity: input = t&1 (t=0 reads slab 0 = h_init), output = ~t&1
            const f16* slab_in  = hX + (size_t)(t & 1) * SLABSZ;
            f16*       slab_out = hX + (size_t)((t + 1) & 1) * SLABSZ;
            const f16* xt = x16 + (size_t)t * I_DIMM;

            f32x4 acc[2][2];   // [ct][btl]
            #pragma unroll
            for (int ct = 0; ct < 2; ++ct)
                #pragma unroll
                for (int btl = 0; btl < 2; ++btl)
                    acc[ct][btl] = (f32x4){0.f, 0.f, 0.f, 0.f};

            // ---- x-part (h-independent): overlaps the barrier wait ----
            #pragma unroll
            for (int it = 8; it < 10; ++it) {
                const int c  = it * 4 + kq;
                const int xo = c * 32 - 1024 + kg8;
                f16x8 wf0 = *(const f16x8*)&lds_w[0][c][lane][0];
                f16x8 wf1 = *(const f16x8*)&lds_w[1][c][lane][0];
                #pragma unroll
                for (int btl = 0; btl < 2; ++btl) {
                    const int btg = bh * 2 + btl;
                    f16x8 a = *(const f16x8*)(xt + (size_t)(n + 16 * btg) * (T_DIM * I_DIMM) + xo);
                    acc[0][btl] = __builtin_amdgcn_mfma_f32_16x16x32_f16(a, wf0, acc[0][btl], 0, 0, 0);
                    acc[1][btl] = __builtin_amdgcn_mfma_f32_16x16x32_f16(a, wf1, acc[1][btl], 0, 0, 0);
                }
            }

            // ---- grid barrier wait (padded flags, 1:1 poll) ----
            if (tid < NBLK) {
                while (__hip_atomic_load(&flags[tid * FSTRIDE],
                                         __ATOMIC_RELAXED, __HIP_MEMORY_SCOPE_AGENT) < stepv)
                    __builtin_amdgcn_s_sleep(1);
            }
            __syncthreads();

            // ---- h burst: 16 fragments (32 x 8B sc1), block-major slab ----
            // chunk c = it*4+kq covers h-cols [c*32+kg8, +8) -> producer block
            // pb = it*16 + kq*4 + kg; fragment = 16B at (pb, row=n+16*btg).
            u64 hb[32];
            #pragma unroll
            for (int it = 0; it < 8; ++it) {
                const int pb = it * 16 + kq * 4 + kg;
                #pragma unroll
                for (int btl = 0; btl < 2; ++btl) {
                    const int btg = bh * 2 + btl;
                    const u64* p = (const u64*)slab_in + (((size_t)pb * 64 + n + 16 * btg) << 1);
                    hb[(it * 2 + btl) * 2 + 0] =
                        __hip_atomic_load(p,     __ATOMIC_RELAXED, __HIP_MEMORY_SCOPE_AGENT);
                    hb[(it * 2 + btl) * 2 + 1] =
                        __hip_atomic_load(p + 1, __ATOMIC_RELAXED, __HIP_MEMORY_SCOPE_AGENT);
                }
            }

            // ---- h-part MFMAs ----
            #pragma unroll
            for (int it = 0; it < 8; ++it) {
                const int c = it * 4 + kq;
                f16x8 wf0 = *(const f16x8*)&lds_w[0][c][lane][0];
                f16x8 wf1 = *(const f16x8*)&lds_w[1][c][lane][0];
                #pragma unroll
                for (int btl = 0; btl < 2; ++btl) {
                    union { u64 u[2]; f16x8 v; } U;
                    U.u[0] = hb[(it * 2 + btl) * 2 + 0];
                    U.u[1] = hb[(it * 2 + btl) * 2 + 1];
                    acc[0][btl] = __builtin_amdgcn_mfma_f32_16x16x32_f16(U.v, wf0, acc[0][btl], 0, 0, 0);
                    acc[1][btl] = __builtin_amdgcn_mfma_f32_16x16x32_f16(U.v, wf1, acc[1][btl], 0, 0, 0);
                }
            }

            // partials: D row = (bh*2+btl)*16 + kg*4 + r, col = ct*16 + n
            #pragma unroll
            for (int ct = 0; ct < 2; ++ct)
                #pragma unroll
                for (int btl = 0; btl < 2; ++btl)
                    #pragma unroll
                    for (int r = 0; r < 4; ++r)
                        gpart[kq][(bh * 2 + btl) * 16 + kg * 4 + r][ct * 16 + n] = acc[ct][btl][r];
            __syncthreads();

            // ---- activations + state update: one (batch, col) per thread ----
            {
                float pre[4];
                #pragma unroll
                for (int g = 0; g < 4; ++g)
                    pre[g] = gpart[0][ab][g * 8 + aj] + gpart[1][ab][g * 8 + aj]
                           + gpart[2][ab][g * 8 + aj] + gpart[3][ab][g * 8 + aj] + bsum[g];
                const float i_ = fsig(pre[0]);
                const float f_ = fsig(pre[1]);
                const float g_ = ftanh(pre[2]);
                const float o_ = fsig(pre[3]);
                c_reg = f_ * c_reg + i_ * g_;
                h_lds[ab][aj] = (f16)(o_ * ftanh(c_reg));
            }
            __syncthreads();

            // ---- publish: contiguous 1 KB (8 exclusive lines) per block ----
            if (tid < 128) {
                const int b = tid >> 1, half = tid & 1;
                u64 v = *(const u64*)&h_lds[b][half * 4];
                u64* dst = (u64*)slab_out + (((size_t)blk * 64 + b) << 1) + half;
                __hip_atomic_store(dst, v, __ATOMIC_RELAXED, __HIP_MEMORY_SCOPE_AGENT);
            }
            // write-through: vmcnt(0) => globally visible (no wbl2 needed)
            asm volatile("s_waitcnt vmcnt(0)" ::: "memory");
            __syncthreads();

            ++stepv;
            if (tid == 0)
                __hip_atomic_store(&flags[blk * FSTRIDE], stepv,
                                   __ATOMIC_RELAXED, __HIP_MEMORY_SCOPE_AGENT);
        }
    }
}

// Tail MLP: a = PReLU(additional @ fcc_W^T + fcc_b); out[b] = [dh, a] @ fc_W^T + fc_b
// Final dec h is slab 0 (last step t=255 odd -> out parity 0), block-major:
// dh[b][k] = hX[k>>3][b][k&7]
__global__ __launch_bounds__(256) void tail_kernel(
    const f16* __restrict__ hX,        // [NBLK][64][8] (slab 0)
    const float* __restrict__ addl,    // [64][128]
    const float* __restrict__ fccW,    // [256][128]
    const float* __restrict__ fccb,    // [256]
    const float* __restrict__ fcW,     // [1][1280]
    const float* __restrict__ fcb,     // [1]
    const float* __restrict__ prelu_a, // [1]
    float* __restrict__ out)           // [64]
{
    __shared__ float a_lds[256];
    __shared__ float red[256];
    const int b = blockIdx.x;
    const int t = threadIdx.x;

    float s = fccb[t];
    const float* wr = fccW + t * 128;
    const float* ar = addl + b * 128;
    #pragma unroll 4
    for (int k = 0; k < 128; ++k) s += ar[k] * wr[k];
    const float pa = *prelu_a;
    a_lds[t] = (s >= 0.f) ? s : pa * s;
    __syncthreads();

    float acc = 0.f;
    for (int k = t; k < 1024; k += 256)
        acc += (float)hX[((size_t)(k >> 3) * 64 + b) * 8 + (k & 7)] * fcW[k];
    acc += a_lds[t] * fcW[1024 + t];
    red[t] = acc;
    __syncthreads();
    for (int sft = 128; sft > 0; sft >>= 1) {
        if (t < sft) red[t] += red[t + sft];
        __syncthreads();
    }
    if (t == 0) out[b] = red[0] + fcb[0];
}

extern "C" void kernel_launch(void* const* d_in, const int* in_sizes, int n_in,
                              void* d_out, int out_size, void* d_ws, size_t ws_size,
                              hipStream_t stream)
{
    const float* x       = (const float*)d_in[0];
    const float* addl    = (const float*)d_in[1];
    const float* enc_Wih = (const float*)d_in[2];
    const float* enc_Whh = (const float*)d_in[3];
    const float* enc_bih = (const float*)d_in[4];
    const float* enc_bhh = (const float*)d_in[5];
    const float* dec_Wih = (const float*)d_in[6];
    const float* dec_Whh = (const float*)d_in[7];
    const float* dec_bih = (const float*)d_in[8];
    const float* dec_bhh = (const float*)d_in[9];
    const float* fcc_W   = (const float*)d_in[10];
    const float* fcc_b   = (const float*)d_in[11];
    const float* fc_W    = (const float*)d_in[12];
    const float* fc_b    = (const float*)d_in[13];
    const float* prelu_a = (const float*)d_in[14];

    char* wsb = (char*)d_ws;
    const size_t W16_BYTES  = (size_t)4 * H_DIM * K_DIM * sizeof(f16);   // 10.5 MB
    const size_t X16_BYTES  = (size_t)B_DIM * T_DIM * I_DIMM * sizeof(f16);
    const size_t SLAB_BYTES = (size_t)SLABSZ * sizeof(f16);              // 128 KB

    f16* W16e = (f16*)wsb;                      wsb += W16_BYTES;
    f16* W16d = (f16*)wsb;                      wsb += W16_BYTES;
    f16* x16  = (f16*)wsb;                      wsb += X16_BYTES;
    f16* hX   = (f16*)wsb;                      wsb += 2 * SLAB_BYTES;
    unsigned* flags = (unsigned*)wsb;

    // One-time (per call) conversions + state init.
    conv_w_kernel<<<4 * H_DIM, 256, 0, stream>>>(enc_Whh, enc_Wih, W16e);
    conv_w_kernel<<<4 * H_DIM, 256, 0, stream>>>(dec_Whh, dec_Wih, W16d);
    conv_x_kernel<<<(B_DIM * T_DIM * I_DIMM / 4 + 255) / 256, 256, 0, stream>>>(
        x, x16, B_DIM * T_DIM * I_DIMM / 4);
    hipMemsetAsync(hX, 0, SLAB_BYTES, stream);                    // slab 0 = h_init = 0
    hipMemsetAsync(flags, 0, NBLK * FSTRIDE * sizeof(unsigned), stream);

    // Persistent cooperative kernel: both LSTMs, 512 steps, one launch.
    {
        void* args[] = { &hX, &x16, &W16e, &W16d,
                         &enc_bih, &enc_bhh, &dec_bih, &dec_bhh, &flags };
        hipLaunchCooperativeKernel((void*)lstm_persistent, dim3(NBLK), dim3(512),
                                   args, 0, stream);
    }

    // Final dec h is slab 0 (t=255 odd -> out parity 0).
    tail_kernel<<<64, 256, 0, stream>>>(hX, addl, fcc_W, fcc_b, fc_W, fc_b,
                                        prelu_a, (float*)d_out);
}

// Round 14
// 2296.099 us; speedup vs baseline: 2.6306x; 1.1130x over previous
//
#include <hip/hip_runtime.h>
#include <cmath>

typedef _Float16 f16;
typedef _Float16 f16x8 __attribute__((ext_vector_type(8)));
typedef _Float16 f16x4 __attribute__((ext_vector_type(4)));
typedef float f32x4 __attribute__((ext_vector_type(4)));
typedef unsigned long long u64;

#define H_DIM 1024
#define I_DIMM 256
#define B_DIM 64
#define T_DIM 256
#define K_DIM 1280
#define NBLK 128                  // blocks; each owns 8 h-cols
#define SLABSZ (NBLK * 64 * 8)    // one h slab, f16 elements (128 KB)
#define FSTRIDE 64                // flag padding: 64 u32 = 256 B per block

// Build W16[4096][1280] = fp16([Whh | Wih]) row-major. grid = 4096 blocks.
__global__ __launch_bounds__(256) void conv_w_kernel(const float* __restrict__ Whh,
                                                     const float* __restrict__ Wih,
                                                     f16* __restrict__ W16) {
    const int r = blockIdx.x;
    const int tid = threadIdx.x;
    const float* hh = Whh + (size_t)r * H_DIM;
    const float* ih = Wih + (size_t)r * I_DIMM;
    f16* dst = W16 + (size_t)r * K_DIM;
    for (int k = tid; k < K_DIM; k += 256)
        dst[k] = (f16)(k < H_DIM ? hh[k] : ih[k - H_DIM]);
}

// x fp32 -> fp16, vectorized 4-wide. n4 = total/4.
__global__ __launch_bounds__(256) void conv_x_kernel(const float* __restrict__ x,
                                                     f16* __restrict__ x16, int n4) {
    const int i = blockIdx.x * 256 + threadIdx.x;
    if (i < n4) {
        float4 v = ((const float4*)x)[i];
        f16x4 o;
        o[0] = (f16)v.x; o[1] = (f16)v.y; o[2] = (f16)v.z; o[3] = (f16)v.w;
        ((f16x4*)x16)[i] = o;
    }
}

// sigmoid / tanh via v_exp_f32 + v_rcp_f32 (exact identities)
__device__ __forceinline__ float fsig(float x) {
    return __builtin_amdgcn_rcpf(1.f + __builtin_amdgcn_exp2f(-1.442695041f * x));
}
__device__ __forceinline__ float ftanh(float x) {
    return 1.f - 2.f * __builtin_amdgcn_rcpf(1.f + __builtin_amdgcn_exp2f(2.885390082f * x));
}

// Persistent LSTM, both phases, 512 steps, one cooperative launch.
// Base = round-13 verified kernel (2.56 ms). ROUND-14 CHANGES (latency chain):
//   (1) per-wave poll: wave (kq) polls exactly its 32 producer flags
//       (pb = it*16+kq*4+kg) with a ballot loop -> no post-poll __syncthreads;
//       each wave's burst starts when ITS producers are ready. Block-level
//       barrier semantics preserved at the gpart sync (union of waves' polls
//       covers all 128 flags) -> publish-overwrite safety unchanged.
//   (2) sched_barrier(0) between the 32-load h burst and the MFMAs -> full
//       load window, one LLC latency instead of several serialized batches.
//   (3) publish tail by wave 0 only (2 x u64 per lane = the whole 1 KB chunk),
//       per-wave vmcnt(0), lane-0 flag store -> waves 1-7 run ahead into the
//       next step's x-part; final __syncthreads deleted (2 syncs/step).
__global__ __launch_bounds__(512, 1) void lstm_persistent(
    f16* __restrict__ hX,            // [2][NBLK][64][8] ping-pong slabs
    const f16* __restrict__ x16,     // [64][256][256]
    const f16* __restrict__ W16e,    // [4096][1280]
    const f16* __restrict__ W16d,    // [4096][1280]
    const float* __restrict__ enc_bih, const float* __restrict__ enc_bhh,
    const float* __restrict__ dec_bih, const float* __restrict__ dec_bhh,
    unsigned* __restrict__ flags)    // [NBLK*FSTRIDE], zeroed each call
{
    __shared__ __align__(16) f16 lds_w[2][40][64][8];   // 80 KB  [ct][chunk][lane][8]
    __shared__ float gpart[4][64][34];                  // 34.8 KB [kq][batch][gatecol]
    __shared__ __align__(16) f16 h_lds[64][8];          // 1 KB

    const int tid  = threadIdx.x;
    const int blk  = blockIdx.x;
    const int w    = tid >> 6;
    const int bh   = w >> 2;              // batch half (0: rows 0-31, 1: 32-63)
    const int kq   = w & 3;               // K quarter
    const int lane = tid & 63;
    const int n    = lane & 15;
    const int kg   = lane >> 4;
    const int kg8  = kg * 8;

    // this wave's producer-flag address for the poll (lanes mod 32 -> 32 blocks)
    const int pl   = lane & 31;
    const unsigned* fpoll = &flags[(((pl >> 2) * 16) + kq * 4 + (pl & 3)) * FSTRIDE];

    // W rows for this lane's two column-tiles (gate-col = ct*16 + n)
    int rW[2];
    #pragma unroll
    for (int ct = 0; ct < 2; ++ct) {
        const int gc = ct * 16 + n;
        rW[ct] = (gc >> 3) * H_DIM + blk * 8 + (gc & 7);
    }

    // activation-thread mapping: one (batch, col) per thread
    const int ab   = tid >> 3;
    const int aj   = tid & 7;
    const int acol = blk * 8 + aj;

    float c_reg = 0.f;                    // cell state, carries enc -> dec
    unsigned stepv = 0;                   // monotone barrier epoch

    #pragma unroll 1
    for (int phase = 0; phase < 2; ++phase) {
        const f16* W  = phase ? W16d : W16e;
        const float* bi = phase ? dec_bih : enc_bih;
        const float* bhp = phase ? dec_bhh : enc_bhh;

        float bsum[4];
        #pragma unroll
        for (int g = 0; g < 4; ++g)
            bsum[g] = bi[g * H_DIM + acol] + bhp[g * H_DIM + acol];

        // Stage W chunks: bh=0 waves stage iters 0..4, bh=1 waves iters 5..9.
        // (safe without a pre-sync: all lds_w reads of the previous phase
        //  precede sync A of its last step; publish doesn't touch lds_w)
        {
            const int it0 = bh * 5;
            #pragma unroll 1
            for (int i = 0; i < 5; ++i) {
                const int c = (it0 + i) * 4 + kq;
                #pragma unroll
                for (int ct = 0; ct < 2; ++ct)
                    *(f16x8*)&lds_w[ct][c][lane][0] =
                        *(const f16x8*)(W + (size_t)rW[ct] * K_DIM + c * 32 + kg8);
            }
        }
        __syncthreads();

        #pragma unroll 1
        for (int t = 0; t < T_DIM; ++t) {
            // slab parity: input = t&1 (t=0 reads slab 0 = h_init), output = ~t&1
            const f16* slab_in  = hX + (size_t)(t & 1) * SLABSZ;
            f16*       slab_out = hX + (size_t)((t + 1) & 1) * SLABSZ;
            const f16* xt = x16 + (size_t)t * I_DIMM;

            f32x4 acc[2][2];   // [ct][btl]
            #pragma unroll
            for (int ct = 0; ct < 2; ++ct)
                #pragma unroll
                for (int btl = 0; btl < 2; ++btl)
                    acc[ct][btl] = (f32x4){0.f, 0.f, 0.f, 0.f};

            // ---- x-part (h-independent): overlaps the producers' tail ----
            #pragma unroll
            for (int it = 8; it < 10; ++it) {
                const int c  = it * 4 + kq;
                const int xo = c * 32 - 1024 + kg8;
                f16x8 wf0 = *(const f16x8*)&lds_w[0][c][lane][0];
                f16x8 wf1 = *(const f16x8*)&lds_w[1][c][lane][0];
                #pragma unroll
                for (int btl = 0; btl < 2; ++btl) {
                    const int btg = bh * 2 + btl;
                    f16x8 a = *(const f16x8*)(xt + (size_t)(n + 16 * btg) * (T_DIM * I_DIMM) + xo);
                    acc[0][btl] = __builtin_amdgcn_mfma_f32_16x16x32_f16(a, wf0, acc[0][btl], 0, 0, 0);
                    acc[1][btl] = __builtin_amdgcn_mfma_f32_16x16x32_f16(a, wf1, acc[1][btl], 0, 0, 0);
                }
            }

            // ---- per-wave poll: wait for THIS wave's 32 producers ----
            while (true) {
                unsigned v = __hip_atomic_load(fpoll, __ATOMIC_RELAXED,
                                               __HIP_MEMORY_SCOPE_AGENT);
                if (__all(v >= stepv)) break;
                __builtin_amdgcn_s_sleep(1);
            }

            // ---- h burst: 16 fragments (32 x 8B sc1), block-major slab ----
            u64 hb[32];
            #pragma unroll
            for (int it = 0; it < 8; ++it) {
                const int pb = it * 16 + kq * 4 + kg;
                #pragma unroll
                for (int btl = 0; btl < 2; ++btl) {
                    const int btg = bh * 2 + btl;
                    const u64* p = (const u64*)slab_in + (((size_t)pb * 64 + n + 16 * btg) << 1);
                    hb[(it * 2 + btl) * 2 + 0] =
                        __hip_atomic_load(p,     __ATOMIC_RELAXED, __HIP_MEMORY_SCOPE_AGENT);
                    hb[(it * 2 + btl) * 2 + 1] =
                        __hip_atomic_load(p + 1, __ATOMIC_RELAXED, __HIP_MEMORY_SCOPE_AGENT);
                }
            }
            __builtin_amdgcn_sched_barrier(0);   // pin all 32 loads before MFMAs

            // ---- h-part MFMAs ----
            #pragma unroll
            for (int it = 0; it < 8; ++it) {
                const int c = it * 4 + kq;
                f16x8 wf0 = *(const f16x8*)&lds_w[0][c][lane][0];
                f16x8 wf1 = *(const f16x8*)&lds_w[1][c][lane][0];
                #pragma unroll
                for (int btl = 0; btl < 2; ++btl) {
                    union { u64 u[2]; f16x8 v; } U;
                    U.u[0] = hb[(it * 2 + btl) * 2 + 0];
                    U.u[1] = hb[(it * 2 + btl) * 2 + 1];
                    acc[0][btl] = __builtin_amdgcn_mfma_f32_16x16x32_f16(U.v, wf0, acc[0][btl], 0, 0, 0);
                    acc[1][btl] = __builtin_amdgcn_mfma_f32_16x16x32_f16(U.v, wf1, acc[1][btl], 0, 0, 0);
                }
            }

            // partials: D row = (bh*2+btl)*16 + kg*4 + r, col = ct*16 + n
            #pragma unroll
            for (int ct = 0; ct < 2; ++ct)
                #pragma unroll
                for (int btl = 0; btl < 2; ++btl)
                    #pragma unroll
                    for (int r = 0; r < 4; ++r)
                        gpart[kq][(bh * 2 + btl) * 16 + kg * 4 + r][ct * 16 + n] = acc[ct][btl][r];
            __syncthreads();   // (A) also completes the block-wide flag view

            // ---- activations + state update: one (batch, col) per thread ----
            {
                float pre[4];
                #pragma unroll
                for (int g = 0; g < 4; ++g)
                    pre[g] = gpart[0][ab][g * 8 + aj] + gpart[1][ab][g * 8 + aj]
                           + gpart[2][ab][g * 8 + aj] + gpart[3][ab][g * 8 + aj] + bsum[g];
                const float i_ = fsig(pre[0]);
                const float f_ = fsig(pre[1]);
                const float g_ = ftanh(pre[2]);
                const float o_ = fsig(pre[3]);
                c_reg = f_ * c_reg + i_ * g_;
                h_lds[ab][aj] = (f16)(o_ * ftanh(c_reg));
            }
            __syncthreads();   // (B) h_lds complete; gpart reads done

            ++stepv;
            // ---- publish tail: wave 0 only; other waves run ahead ----
            if (w == 0) {
                const u64* src = (const u64*)&h_lds[lane][0];
                u64 v0 = src[0], v1 = src[1];
                u64* dst = (u64*)slab_out + (((size_t)blk * 64 + lane) << 1);
                __hip_atomic_store(dst,     v0, __ATOMIC_RELAXED, __HIP_MEMORY_SCOPE_AGENT);
                __hip_atomic_store(dst + 1, v1, __ATOMIC_RELAXED, __HIP_MEMORY_SCOPE_AGENT);
                // wave-0 write-through drain: chunk globally visible
                asm volatile("s_waitcnt vmcnt(0)" ::: "memory");
                if (lane == 0)
                    __hip_atomic_store(&flags[blk * FSTRIDE], stepv,
                                       __ATOMIC_RELAXED, __HIP_MEMORY_SCOPE_AGENT);
            }
            // next iteration's sync A rejoins wave 0 before any h_lds/gpart reuse
        }
    }
}

// Tail MLP: a = PReLU(additional @ fcc_W^T + fcc_b); out[b] = [dh, a] @ fc_W^T + fc_b
// Final dec h is slab 0 (last step t=255 odd -> out parity 0), block-major:
// dh[b][k] = hX[k>>3][b][k&7]
__global__ __launch_bounds__(256) void tail_kernel(
    const f16* __restrict__ hX,        // [NBLK][64][8] (slab 0)
    const float* __restrict__ addl,    // [64][128]
    const float* __restrict__ fccW,    // [256][128]
    const float* __restrict__ fccb,    // [256]
    const float* __restrict__ fcW,     // [1][1280]
    const float* __restrict__ fcb,     // [1]
    const float* __restrict__ prelu_a, // [1]
    float* __restrict__ out)           // [64]
{
    __shared__ float a_lds[256];
    __shared__ float red[256];
    const int b = blockIdx.x;
    const int t = threadIdx.x;

    float s = fccb[t];
    const float* wr = fccW + t * 128;
    const float* ar = addl + b * 128;
    #pragma unroll 4
    for (int k = 0; k < 128; ++k) s += ar[k] * wr[k];
    const float pa = *prelu_a;
    a_lds[t] = (s >= 0.f) ? s : pa * s;
    __syncthreads();

    float acc = 0.f;
    for (int k = t; k < 1024; k += 256)
        acc += (float)hX[((size_t)(k >> 3) * 64 + b) * 8 + (k & 7)] * fcW[k];
    acc += a_lds[t] * fcW[1024 + t];
    red[t] = acc;
    __syncthreads();
    for (int sft = 128; sft > 0; sft >>= 1) {
        if (t < sft) red[t] += red[t + sft];
        __syncthreads();
    }
    if (t == 0) out[b] = red[0] + fcb[0];
}

extern "C" void kernel_launch(void* const* d_in, const int* in_sizes, int n_in,
                              void* d_out, int out_size, void* d_ws, size_t ws_size,
                              hipStream_t stream)
{
    const float* x       = (const float*)d_in[0];
    const float* addl    = (const float*)d_in[1];
    const float* enc_Wih = (const float*)d_in[2];
    const float* enc_Whh = (const float*)d_in[3];
    const float* enc_bih = (const float*)d_in[4];
    const float* enc_bhh = (const float*)d_in[5];
    const float* dec_Wih = (const float*)d_in[6];
    const float* dec_Whh = (const float*)d_in[7];
    const float* dec_bih = (const float*)d_in[8];
    const float* dec_bhh = (const float*)d_in[9];
    const float* fcc_W   = (const float*)d_in[10];
    const float* fcc_b   = (const float*)d_in[11];
    const float* fc_W    = (const float*)d_in[12];
    const float* fc_b    = (const float*)d_in[13];
    const float* prelu_a = (const float*)d_in[14];

    char* wsb = (char*)d_ws;
    const size_t W16_BYTES  = (size_t)4 * H_DIM * K_DIM * sizeof(f16);   // 10.5 MB
    const size_t X16_BYTES  = (size_t)B_DIM * T_DIM * I_DIMM * sizeof(f16);
    const size_t SLAB_BYTES = (size_t)SLABSZ * sizeof(f16);              // 128 KB

    f16* W16e = (f16*)wsb;                      wsb += W16_BYTES;
    f16* W16d = (f16*)wsb;                      wsb += W16_BYTES;
    f16* x16  = (f16*)wsb;                      wsb += X16_BYTES;
    f16* hX   = (f16*)wsb;                      wsb += 2 * SLAB_BYTES;
    unsigned* flags = (unsigned*)wsb;

    // One-time (per call) conversions + state init.
    conv_w_kernel<<<4 * H_DIM, 256, 0, stream>>>(enc_Whh, enc_Wih, W16e);
    conv_w_kernel<<<4 * H_DIM, 256, 0, stream>>>(dec_Whh, dec_Wih, W16d);
    conv_x_kernel<<<(B_DIM * T_DIM * I_DIMM / 4 + 255) / 256, 256, 0, stream>>>(
        x, x16, B_DIM * T_DIM * I_DIMM / 4);
    hipMemsetAsync(hX, 0, SLAB_BYTES, stream);                    // slab 0 = h_init = 0
    hipMemsetAsync(flags, 0, NBLK * FSTRIDE * sizeof(unsigned), stream);

    // Persistent cooperative kernel: both LSTMs, 512 steps, one launch.
    {
        void* args[] = { &hX, &x16, &W16e, &W16d,
                         &enc_bih, &enc_bhh, &dec_bih, &dec_bhh, &flags };
        hipLaunchCooperativeKernel((void*)lstm_persistent, dim3(NBLK), dim3(512),
                                   args, 0, stream);
    }

    // Final dec h is slab 0 (t=255 odd -> out parity 0).
    tail_kernel<<<64, 256, 0, stream>>>(hX, addl, fcc_W, fcc_b, fc_W, fc_b,
                                        prelu_a, (float*)d_out);
}